// Round 9
// baseline (159.740 us; speedup 1.0000x reference)
//
#include <hip/hip_runtime.h>
#include <hip/hip_bf16.h>
#include <cmath>

#define B_ 8
#define T_ 2048
#define D_ 1024
#define H_ 64

typedef __bf16 bf16x8 __attribute__((ext_vector_type(8)));
typedef __bf16 bf16x4 __attribute__((ext_vector_type(4)));
typedef float f32x4 __attribute__((ext_vector_type(4)));

// q scaled by 1/sqrt(64) * log2(e) so softmax runs in exp2 domain
#define QSCALE 0.18033688011112042f

// async global->LDS, 16B per lane, lands at (wave-uniform lds base) + lane*16
__device__ __forceinline__ void async_copy16(const void* g, void* lds) {
  __builtin_amdgcn_global_load_lds(
      (const __attribute__((address_space(1))) unsigned int*)g,
      (__attribute__((address_space(3))) unsigned int*)lds,
      16, 0, 0);
}

// ---------------------------------------------------------------------------
// Kernel 1: cast + transpose weights via LDS: Wt[mat][h=64][d=1024] bf16
// ---------------------------------------------------------------------------
__global__ __launch_bounds__(256)
void castw_kernel(const float* __restrict__ w0,
                  const float* __restrict__ w1,
                  const float* __restrict__ w2,
                  __bf16* __restrict__ Wt) {
  __shared__ float tile[64][65];
  const int mat = blockIdx.y;
  const float* w = (mat == 0) ? w0 : (mat == 1) ? w1 : w2;
  const int d0 = blockIdx.x * 64;
  const int t = threadIdx.x;
#pragma unroll
  for (int i = 0; i < 16; i++) {
    int idx = i * 256 + t;
    int dl = idx >> 6, h = idx & 63;
    tile[dl][h] = w[(size_t)(d0 + dl) * 64 + h];
  }
  __syncthreads();
  const int h = t >> 2;
  const int dc = (t & 3) * 16;
  bf16x8 o0, o1;
#pragma unroll
  for (int j = 0; j < 8; j++) {
    o0[j] = (__bf16)tile[dc + j][h];
    o1[j] = (__bf16)tile[dc + 8 + j][h];
  }
  bf16x8* dst = (bf16x8*)(Wt + (size_t)mat * 65536 + (size_t)h * 1024 + d0 + dc);
  dst[0] = o0;
  dst[1] = o1;
}

// ---------------------------------------------------------------------------
// Kernel 2: fused QKV projection, BARRIER-FREE K-loop.
// grid 512, block 256, M=32/block, N=192, K in 8 slices of 128.
// Insight: W staging is wave-private (wave wv reads exactly cols
// [wv*48,wv*48+48) which it stages itself), and x A-frags are gathered
// directly from global fp32 into VGPRs (L3-resident) -> NO __syncthreads in
// the K-loop. Each wave: issue async W + x gathers, per-wave s_waitcnt(0),
// compute. Stalls are per-wave, not block-wide: resident waves desync and
// cover each other's drains (the thing v7/v8's block barrier could never do;
// v8 post-mortem: occupancy doesn't fix block-wide drains).
// LDS = 48 KB (W only) -> all 512 blocks resident.
// ---------------------------------------------------------------------------
__global__ __launch_bounds__(256)
void proj_kernel(const float* __restrict__ x,
                 const __bf16* __restrict__ Wt,
                 const float* __restrict__ bq,
                 const float* __restrict__ bk,
                 const float* __restrict__ bv,
                 __bf16* __restrict__ qb,
                 __bf16* __restrict__ kb,
                 __bf16* __restrict__ vt) {
  __shared__ __align__(16) __bf16 wsl[192 * 128];  // 48 KB, wave-private quarters

  const int tid  = threadIdx.x;
  const int wv   = tid >> 6;
  const int lane = tid & 63;
  const int ln   = lane & 15;
  const int quad = lane >> 4;
  const int m0   = blockIdx.x * 32;

  f32x4 acc[6] = {};                 // [mt*3 + nt]

  for (int s = 0; s < 8; s++) {
    const int k0 = s * 128;

    // ---- issue async W staging: wave-private cols [wv*48, wv*48+48) ----
    // Instr i covers rows i*4..i*4+3 x 128 k; source chunk kc = pos ^ (row&15)
    // -> XOR-swizzled LDS image (conflict-free frag reads, as v7).
#pragma unroll
    for (int j = 0; j < 12; j++) {
      int i = wv * 12 + j;
      int grow = i * 4 + (lane >> 4);
      int kc = (lane & 15) ^ (grow & 15);
      const __bf16* gp = Wt + (size_t)grow * 1024 + k0 + kc * 8;
      async_copy16(gp, wsl + i * 512);
    }

    // ---- gather x A-frags directly (fp32, L3-resident), cvt in-register ----
    float4 xg[16];
#pragma unroll
    for (int mt = 0; mt < 2; mt++)
#pragma unroll
      for (int ks = 0; ks < 4; ks++)
#pragma unroll
        for (int h = 0; h < 2; h++)
          xg[mt * 8 + ks * 2 + h] = *(const float4*)(
              x + (size_t)(m0 + mt * 16 + ln) * D_ + k0 + ks * 32 + quad * 8 + h * 4);

    // per-WAVE drain of async W + x gathers (no block barrier!)
    __builtin_amdgcn_s_waitcnt(0);
    __builtin_amdgcn_sched_barrier(0);
    __asm__ volatile("" ::: "memory");

    bf16x8 af[2][4];
#pragma unroll
    for (int mt = 0; mt < 2; mt++)
#pragma unroll
      for (int ks = 0; ks < 4; ks++) {
        float4 a0 = xg[mt * 8 + ks * 2];
        float4 a1 = xg[mt * 8 + ks * 2 + 1];
        af[mt][ks][0] = (__bf16)a0.x; af[mt][ks][1] = (__bf16)a0.y;
        af[mt][ks][2] = (__bf16)a0.z; af[mt][ks][3] = (__bf16)a0.w;
        af[mt][ks][4] = (__bf16)a1.x; af[mt][ks][5] = (__bf16)a1.y;
        af[mt][ks][6] = (__bf16)a1.z; af[mt][ks][7] = (__bf16)a1.w;
      }

    // ---- compute: 24 MFMAs per wave per slice ----
#pragma unroll
    for (int ks = 0; ks < 4; ks++)
#pragma unroll
      for (int nt = 0; nt < 3; nt++) {
        int col = wv * 48 + nt * 16 + ln;
        bf16x8 bf = *(const bf16x8*)(wsl + col * 128 + (((ks * 4 + quad) ^ (col & 15)) * 8));
#pragma unroll
        for (int mt = 0; mt < 2; mt++)
          acc[mt * 3 + nt] =
              __builtin_amdgcn_mfma_f32_16x16x32_bf16(af[mt][ks], bf, acc[mt * 3 + nt], 0, 0, 0);
      }
  }

  // ---- epilogue: bias + store (q pre-scaled by QSCALE for exp2 softmax) ----
#pragma unroll
  for (int nt = 0; nt < 3; nt++) {
    int idx = wv * 48 + nt * 16;
    int mat = idx >> 6;
    int h = (idx & 63) + ln;
    float bcol = ((mat == 0) ? bq : (mat == 1) ? bk : bv)[h];
#pragma unroll
    for (int mt = 0; mt < 2; mt++) {
      f32x4 a = acc[mt * 3 + nt];
      int grow0 = m0 + mt * 16 + quad * 4;
      if (mat == 0) {
#pragma unroll
        for (int r = 0; r < 4; r++)
          qb[(size_t)(grow0 + r) * 64 + h] = (__bf16)((a[r] + bcol) * QSCALE);
      } else if (mat == 1) {
#pragma unroll
        for (int r = 0; r < 4; r++)
          kb[(size_t)(grow0 + r) * 64 + h] = (__bf16)(a[r] + bcol);
      } else {
        int bb = grow0 >> 11, t0 = grow0 & 2047;
        bf16x4 pv;
#pragma unroll
        for (int r = 0; r < 4; r++)
          pv[r] = (__bf16)(a[r] + bcol);
        *(bf16x4*)(vt + (size_t)(bb * 64 + h) * T_ + t0) = pv;
      }
    }
  }
}

// ---------------------------------------------------------------------------
// Kernel 3: causal flash attention, DUAL q-tile per block (UNCHANGED from
// v7/v8 for clean attribution of the proj delta).
// ---------------------------------------------------------------------------
__global__ __launch_bounds__(256)
void attn_kernel(const __bf16* __restrict__ qb,
                 const __bf16* __restrict__ kb,
                 const __bf16* __restrict__ vt,
                 float* __restrict__ out) {
  __shared__ __align__(16) __bf16 pA[2][4][16][72];  // [lo/hi][wave][row][col]
  __shared__ float ml_m[4][16];
  __shared__ float ml_l[4][16];
  __shared__ float olds[4][16][64];

  const int tid   = threadIdx.x;
  const int wv    = tid >> 6;
  const int lane  = tid & 63;
  const int ln    = lane & 15;
  const int quad  = lane >> 4;
  const int b     = blockIdx.y;

  const int p     = ((blockIdx.y >> 2) & 1) ? blockIdx.x : 63 - blockIdx.x;
  const int jqL   = p, jqH = 127 - p;
  const int qbL   = jqL * 16, qbH = jqH * 16;
  const int ntL   = (jqL >> 2) + 1;
  const int ntH   = (jqH >> 2) + 1;

  const __bf16* Q = qb + (size_t)b * T_ * 64;
  const __bf16* K = kb + (size_t)b * T_ * 64;
  const __bf16* V = vt + (size_t)b * 64 * T_;

  bf16x8 qaL0 = *(const bf16x8*)(Q + (qbL + ln) * 64 + quad * 8);
  bf16x8 qaL1 = *(const bf16x8*)(Q + (qbL + ln) * 64 + 32 + quad * 8);
  bf16x8 qaH0 = *(const bf16x8*)(Q + (qbH + ln) * 64 + quad * 8);
  bf16x8 qaH1 = *(const bf16x8*)(Q + (qbH + ln) * 64 + 32 + quad * 8);

  f32x4 accL[4] = {}, accH[4] = {};
  float mL = -INFINITY, lL = 0.f, mH = -INFINITY, lH = 0.f;

  bf16x8 kfa[4], kfb[4], vfa[4], vfb[4];
#pragma unroll
  for (int h = 0; h < 4; h++) {
    const __bf16* kr = K + (size_t)(wv * 64 + h * 16 + ln) * 64 + quad * 8;
    kfa[h] = *(const bf16x8*)kr;
    kfb[h] = *(const bf16x8*)(kr + 32);
  }

  int jt = wv;

  // ---- phase 1: both q-tiles share K/V fragments ----
  for (; jt < ntL; jt += 4) {
    const int kv0 = jt * 64;

    f32x4 sH[4] = {}, sL[4] = {};
#pragma unroll
    for (int h = 0; h < 4; h++) {
      sH[h] = __builtin_amdgcn_mfma_f32_16x16x32_bf16(kfa[h], qaH0, sH[h], 0, 0, 0);
      sH[h] = __builtin_amdgcn_mfma_f32_16x16x32_bf16(kfb[h], qaH1, sH[h], 0, 0, 0);
      sL[h] = __builtin_amdgcn_mfma_f32_16x16x32_bf16(kfa[h], qaL0, sL[h], 0, 0, 0);
      sL[h] = __builtin_amdgcn_mfma_f32_16x16x32_bf16(kfb[h], qaL1, sL[h], 0, 0, 0);
    }

    if (jt + 4 < ntH) {
#pragma unroll
      for (int h = 0; h < 4; h++) {
        const __bf16* kr = K + (size_t)(kv0 + 256 + h * 16 + ln) * 64 + quad * 8;
        kfa[h] = *(const bf16x8*)kr;
        kfb[h] = *(const bf16x8*)(kr + 32);
      }
    }
#pragma unroll
    for (int nt = 0; nt < 4; nt++) {
      const __bf16* vr = V + (size_t)(nt * 16 + ln) * T_ + kv0 + quad * 8;
      vfa[nt] = *(const bf16x8*)vr;
      vfb[nt] = *(const bf16x8*)(vr + 32);
    }

    if (jt == ntL - 1) {
      const int lim = qbL + ln - kv0 - quad * 4;
#pragma unroll
      for (int h = 0; h < 4; h++)
#pragma unroll
        for (int r = 0; r < 4; r++)
          if (h * 16 + r > lim) sL[h][r] = -INFINITY;
    }

    float mxH = sH[0][0], mxL = sL[0][0];
#pragma unroll
    for (int h = 0; h < 4; h++)
#pragma unroll
      for (int r = 0; r < 4; r++) {
        mxH = fmaxf(mxH, sH[h][r]);
        mxL = fmaxf(mxL, sL[h][r]);
      }
    mxH = fmaxf(mxH, __shfl_xor(mxH, 16));
    mxL = fmaxf(mxL, __shfl_xor(mxL, 16));
    mxH = fmaxf(mxH, __shfl_xor(mxH, 32));
    mxL = fmaxf(mxL, __shfl_xor(mxL, 32));

    float mnH = fmaxf(mH, mxH), mnL = fmaxf(mL, mxL);
    float alH = __builtin_amdgcn_exp2f(mH - mnH);
    float alL = __builtin_amdgcn_exp2f(mL - mnL);
    mH = mnH; mL = mnL;

    float pH[4][4], pL[4][4], smH = 0.f, smL = 0.f;
#pragma unroll
    for (int h = 0; h < 4; h++)
#pragma unroll
      for (int r = 0; r < 4; r++) {
        pH[h][r] = __builtin_amdgcn_exp2f(sH[h][r] - mnH);
        pL[h][r] = __builtin_amdgcn_exp2f(sL[h][r] - mnL);
        smH += pH[h][r];
        smL += pL[h][r];
      }
    smH += __shfl_xor(smH, 16);  smL += __shfl_xor(smL, 16);
    smH += __shfl_xor(smH, 32);  smL += __shfl_xor(smL, 32);
    lH = lH * alH + smH;
    lL = lL * alL + smL;

    float arH[4], arL[4];
#pragma unroll
    for (int r = 0; r < 4; r++) {
      arH[r] = __shfl(alH, quad * 4 + r);
      arL[r] = __shfl(alL, quad * 4 + r);
    }
#pragma unroll
    for (int nt = 0; nt < 4; nt++)
#pragma unroll
      for (int r = 0; r < 4; r++) {
        accH[nt][r] *= arH[r];
        accL[nt][r] *= arL[r];
      }

#pragma unroll
    for (int h = 0; h < 4; h++) {
      bf16x4 ph, pl;
#pragma unroll
      for (int r = 0; r < 4; r++) { ph[r] = (__bf16)pH[h][r]; pl[r] = (__bf16)pL[h][r]; }
      *(bf16x4*)(&pA[1][wv][ln][h * 16 + quad * 4]) = ph;
      *(bf16x4*)(&pA[0][wv][ln][h * 16 + quad * 4]) = pl;
    }
    bf16x8 paH0 = *(const bf16x8*)(&pA[1][wv][ln][quad * 8]);
    bf16x8 paH1 = *(const bf16x8*)(&pA[1][wv][ln][32 + quad * 8]);
    bf16x8 paL0 = *(const bf16x8*)(&pA[0][wv][ln][quad * 8]);
    bf16x8 paL1 = *(const bf16x8*)(&pA[0][wv][ln][32 + quad * 8]);
#pragma unroll
    for (int nt = 0; nt < 4; nt++) {
      accH[nt] = __builtin_amdgcn_mfma_f32_16x16x32_bf16(paH0, vfa[nt], accH[nt], 0, 0, 0);
      accH[nt] = __builtin_amdgcn_mfma_f32_16x16x32_bf16(paH1, vfb[nt], accH[nt], 0, 0, 0);
      accL[nt] = __builtin_amdgcn_mfma_f32_16x16x32_bf16(paL0, vfa[nt], accL[nt], 0, 0, 0);
      accL[nt] = __builtin_amdgcn_mfma_f32_16x16x32_bf16(paL1, vfb[nt], accL[nt], 0, 0, 0);
    }
  }

  // ---- phase 2: high tile only ----
  for (; jt < ntH; jt += 4) {
    const int kv0 = jt * 64;

    f32x4 sH[4] = {};
#pragma unroll
    for (int h = 0; h < 4; h++) {
      sH[h] = __builtin_amdgcn_mfma_f32_16x16x32_bf16(kfa[h], qaH0, sH[h], 0, 0, 0);
      sH[h] = __builtin_amdgcn_mfma_f32_16x16x32_bf16(kfb[h], qaH1, sH[h], 0, 0, 0);
    }

    if (jt + 4 < ntH) {
#pragma unroll
      for (int h = 0; h < 4; h++) {
        const __bf16* kr = K + (size_t)(kv0 + 256 + h * 16 + ln) * 64 + quad * 8;
        kfa[h] = *(const bf16x8*)kr;
        kfb[h] = *(const bf16x8*)(kr + 32);
      }
    }
#pragma unroll
    for (int nt = 0; nt < 4; nt++) {
      const __bf16* vr = V + (size_t)(nt * 16 + ln) * T_ + kv0 + quad * 8;
      vfa[nt] = *(const bf16x8*)vr;
      vfb[nt] = *(const bf16x8*)(vr + 32);
    }

    if (jt == ntH - 1) {
      const int lim = qbH + ln - kv0 - quad * 4;
#pragma unroll
      for (int h = 0; h < 4; h++)
#pragma unroll
        for (int r = 0; r < 4; r++)
          if (h * 16 + r > lim) sH[h][r] = -INFINITY;
    }

    float mxH = sH[0][0];
#pragma unroll
    for (int h = 0; h < 4; h++)
#pragma unroll
      for (int r = 0; r < 4; r++) mxH = fmaxf(mxH, sH[h][r]);
    mxH = fmaxf(mxH, __shfl_xor(mxH, 16));
    mxH = fmaxf(mxH, __shfl_xor(mxH, 32));

    float mnH = fmaxf(mH, mxH);
    float alH = __builtin_amdgcn_exp2f(mH - mnH);
    mH = mnH;

    float pH[4][4], smH = 0.f;
#pragma unroll
    for (int h = 0; h < 4; h++)
#pragma unroll
      for (int r = 0; r < 4; r++) {
        pH[h][r] = __builtin_amdgcn_exp2f(sH[h][r] - mnH);
        smH += pH[h][r];
      }
    smH += __shfl_xor(smH, 16);
    smH += __shfl_xor(smH, 32);
    lH = lH * alH + smH;

    float arH[4];
#pragma unroll
    for (int r = 0; r < 4; r++) arH[r] = __shfl(alH, quad * 4 + r);
#pragma unroll
    for (int nt = 0; nt < 4; nt++)
#pragma unroll
      for (int r = 0; r < 4; r++) accH[nt][r] *= arH[r];

#pragma unroll
    for (int h = 0; h < 4; h++) {
      bf16x4 ph;
#pragma unroll
      for (int r = 0; r < 4; r++) ph[r] = (__bf16)pH[h][r];
      *(bf16x4*)(&pA[1][wv][ln][h * 16 + quad * 4]) = ph;
    }
    bf16x8 paH0 = *(const bf16x8*)(&pA[1][wv][ln][quad * 8]);
    bf16x8 paH1 = *(const bf16x8*)(&pA[1][wv][ln][32 + quad * 8]);
#pragma unroll
    for (int nt = 0; nt < 4; nt++) {
      accH[nt] = __builtin_amdgcn_mfma_f32_16x16x32_bf16(paH0, vfa[nt], accH[nt], 0, 0, 0);
      accH[nt] = __builtin_amdgcn_mfma_f32_16x16x32_bf16(paH1, vfb[nt], accH[nt], 0, 0, 0);
    }
  }

  // ---- merge + store: low tile, then high tile (sequential LDS reuse) ----
#pragma unroll
  for (int side = 0; side < 2; side++) {
    const float m_i = side == 0 ? mL : mH;
    const float l_i = side == 0 ? lL : lH;
    const f32x4* acc = side == 0 ? accL : accH;
    const int qbase  = side == 0 ? qbL : qbH;

    __syncthreads();
    if (quad == 0) {
      ml_m[wv][ln] = m_i;
      ml_l[wv][ln] = l_i;
    }
    __syncthreads();

#pragma unroll
    for (int r = 0; r < 4; r++) {
      int row = quad * 4 + r;
      float mstar = fmaxf(fmaxf(ml_m[0][row], ml_m[1][row]),
                          fmaxf(ml_m[2][row], ml_m[3][row]));
      float factor = __builtin_amdgcn_exp2f(ml_m[wv][row] - mstar);
#pragma unroll
      for (int nt = 0; nt < 4; nt++)
        olds[wv][row][nt * 16 + ln] = acc[nt][r] * factor;
    }
    __syncthreads();

    {
      int row = tid >> 4;
      int h0 = (tid & 15) * 4;
      float mstar = fmaxf(fmaxf(ml_m[0][row], ml_m[1][row]),
                          fmaxf(ml_m[2][row], ml_m[3][row]));
      float ltot = 0.f;
#pragma unroll
      for (int w = 0; w < 4; w++)
        ltot += ml_l[w][row] * __builtin_amdgcn_exp2f(ml_m[w][row] - mstar);
      float inv = 1.0f / ltot;
      float4 o = {0.f, 0.f, 0.f, 0.f};
#pragma unroll
      for (int w = 0; w < 4; w++) {
        float4 t = *(const float4*)(&olds[w][row][h0]);
        o.x += t.x; o.y += t.y; o.z += t.z; o.w += t.w;
      }
      o.x *= inv; o.y *= inv; o.z *= inv; o.w *= inv;
      *(float4*)(out + ((size_t)(b * T_ + qbase + row)) * 64 + h0) = o;
    }
  }
}

// ---------------------------------------------------------------------------
extern "C" void kernel_launch(void* const* d_in, const int* in_sizes, int n_in,
                              void* d_out, int out_size, void* d_ws, size_t ws_size,
                              hipStream_t stream) {
  const float* x  = (const float*)d_in[0];
  const float* Wk = (const float*)d_in[1];
  const float* bk = (const float*)d_in[2];
  const float* Wq = (const float*)d_in[3];
  const float* bq = (const float*)d_in[4];
  const float* Wv = (const float*)d_in[5];
  const float* bv = (const float*)d_in[6];
  float* out = (float*)d_out;

  char* ws = (char*)d_ws;
  __bf16* qb = (__bf16*)(ws);                                  // 2 MB (pre-scaled)
  __bf16* kb = (__bf16*)(ws + (size_t)2 * 1024 * 1024);        // 2 MB
  __bf16* vt = (__bf16*)(ws + (size_t)4 * 1024 * 1024);        // 2 MB (transposed)
  __bf16* Wt = (__bf16*)(ws + (size_t)6 * 1024 * 1024);        // 384 KB

  castw_kernel<<<dim3(16, 3), 256, 0, stream>>>(Wq, Wk, Wv, Wt);
  proj_kernel<<<512, 256, 0, stream>>>(x, Wt, bq, bk, bv, qb, kb, vt);
  attn_kernel<<<dim3(64, 8), 256, 0, stream>>>(qb, kb, vt, out);
}

// Round 10
// 142.254 us; speedup vs baseline: 1.1229x; 1.1229x over previous
//
#include <hip/hip_runtime.h>
#include <hip/hip_bf16.h>
#include <cmath>

#define B_ 8
#define T_ 2048
#define D_ 1024
#define H_ 64

typedef __bf16 bf16x8 __attribute__((ext_vector_type(8)));
typedef __bf16 bf16x4 __attribute__((ext_vector_type(4)));
typedef float f32x4 __attribute__((ext_vector_type(4)));

// q scaled by 1/sqrt(64) * log2(e) so softmax runs in exp2 domain
#define QSCALE 0.18033688011112042f

// async global->LDS, 16B per lane, lands at (wave-uniform lds base) + lane*16
__device__ __forceinline__ void async_copy16(const void* g, void* lds) {
  __builtin_amdgcn_global_load_lds(
      (const __attribute__((address_space(1))) unsigned int*)g,
      (__attribute__((address_space(3))) unsigned int*)lds,
      16, 0, 0);
}

// ---------------------------------------------------------------------------
// Kernel 1: cast + transpose weights via LDS: Wt[mat][h=64][d=1024] bf16
// ---------------------------------------------------------------------------
__global__ __launch_bounds__(256)
void castw_kernel(const float* __restrict__ w0,
                  const float* __restrict__ w1,
                  const float* __restrict__ w2,
                  __bf16* __restrict__ Wt) {
  __shared__ float tile[64][65];
  const int mat = blockIdx.y;
  const float* w = (mat == 0) ? w0 : (mat == 1) ? w1 : w2;
  const int d0 = blockIdx.x * 64;
  const int t = threadIdx.x;
#pragma unroll
  for (int i = 0; i < 16; i++) {
    int idx = i * 256 + t;
    int dl = idx >> 6, h = idx & 63;
    tile[dl][h] = w[(size_t)(d0 + dl) * 64 + h];
  }
  __syncthreads();
  const int h = t >> 2;
  const int dc = (t & 3) * 16;
  bf16x8 o0, o1;
#pragma unroll
  for (int j = 0; j < 8; j++) {
    o0[j] = (__bf16)tile[dc + j][h];
    o1[j] = (__bf16)tile[dc + 8 + j][h];
  }
  bf16x8* dst = (bf16x8*)(Wt + (size_t)mat * 65536 + (size_t)h * 1024 + d0 + dc);
  dst[0] = o0;
  dst[1] = o1;
}

// ---------------------------------------------------------------------------
// Kernel 2: fused QKV projection = v7 structure (best measured: ~26 us vs
// v8 44 / v9 45) + x software pipeline. grid 512, block 256, M=32, N=192,
// K in 8 slices of 128, XOR-swizzled async W staging, 2 blocks/CU.
// NEW vs v7: x slice s+1 is global-loaded into registers DURING slice s's
// compute (issued after sync2, drained at next sync1 after ~24 MFMAs of
// cover) instead of between sync1/sync2 where its full latency sat on the
// barrier-to-barrier critical path. LDS-write from regs is cheap.
// ---------------------------------------------------------------------------
__global__ __launch_bounds__(256)
void proj_kernel(const float* __restrict__ x,
                 const __bf16* __restrict__ Wt,
                 const float* __restrict__ bq,
                 const float* __restrict__ bk,
                 const float* __restrict__ bv,
                 __bf16* __restrict__ qb,
                 __bf16* __restrict__ kb,
                 __bf16* __restrict__ vt) {
  __shared__ __align__(16) __bf16 xs[32 * 128];    // 8 KB, swizzled image
  __shared__ __align__(16) __bf16 wsl[192 * 128];  // 48 KB, swizzled image

  const int tid  = threadIdx.x;
  const int wv   = tid >> 6;
  const int lane = tid & 63;
  const int ln   = lane & 15;
  const int quad = lane >> 4;
  const int m0   = blockIdx.x * 32;

  const int xrow = tid >> 4;         // 0..15 (+16 for second half)
  const int xfi  = tid & 15;         // float4 index base (+16 second half)

  f32x4 acc[6] = {};                 // [mt*3 + nt]
  float4 xr[4];                      // pipelined x slice (regs)

  // preload x slice 0
#pragma unroll
  for (int u = 0; u < 2; u++)
#pragma unroll
    for (int kh = 0; kh < 2; kh++)
      xr[u * 2 + kh] = *(const float4*)(
          x + (size_t)(m0 + xrow + u * 16) * D_ + (xfi + kh * 16) * 4);

  for (int s = 0; s < 8; s++) {
    const int k0 = s * 128;
    __syncthreads();                 // prior slice's readers done (drains
                                     // prefetch loads too — long covered)

    // ---- stage W: 12 async 1KB copies per wave (48 total), swizzled ----
#pragma unroll
    for (int j = 0; j < 12; j++) {
      int i = wv * 12 + j;
      int grow = i * 4 + (lane >> 4);
      int kc = (lane & 15) ^ (grow & 15);
      const __bf16* gp = Wt + (size_t)grow * 1024 + k0 + kc * 8;
      async_copy16(gp, wsl + i * 512);
    }

    // ---- write pipelined x regs -> bf16 -> swizzled LDS (no global load
    //      on the sync1->sync2 critical path) ----
#pragma unroll
    for (int u = 0; u < 2; u++)
#pragma unroll
      for (int kh = 0; kh < 2; kh++) {
        int row = xrow + u * 16;
        int fi = xfi + kh * 16;
        float4 f = xr[u * 2 + kh];
        bf16x4 hv;
        hv[0] = (__bf16)f.x; hv[1] = (__bf16)f.y;
        hv[2] = (__bf16)f.z; hv[3] = (__bf16)f.w;
        int ch = fi >> 1, half = fi & 1;
        *(bf16x4*)(xs + row * 128 + ((ch ^ (row & 15)) * 8) + half * 4) = hv;
      }

    __syncthreads();                 // drains async W + xs writes

    // ---- prefetch next slice's x: flies during the MFMA block below ----
    if (s < 7) {
#pragma unroll
      for (int u = 0; u < 2; u++)
#pragma unroll
        for (int kh = 0; kh < 2; kh++)
          xr[u * 2 + kh] = *(const float4*)(
              x + (size_t)(m0 + xrow + u * 16) * D_ + k0 + 128 + (xfi + kh * 16) * 4);
    }

    // ---- compute: 24 MFMAs per wave per slice ----
#pragma unroll
    for (int ks = 0; ks < 4; ks++) {
      bf16x8 af[2];
#pragma unroll
      for (int mt = 0; mt < 2; mt++) {
        int m = mt * 16 + ln;
        af[mt] = *(const bf16x8*)(xs + m * 128 + (((ks * 4 + quad) ^ (m & 15)) * 8));
      }
#pragma unroll
      for (int nt = 0; nt < 3; nt++) {
        int col = wv * 48 + nt * 16 + ln;
        bf16x8 bf = *(const bf16x8*)(wsl + col * 128 + (((ks * 4 + quad) ^ (col & 15)) * 8));
#pragma unroll
        for (int mt = 0; mt < 2; mt++)
          acc[mt * 3 + nt] =
              __builtin_amdgcn_mfma_f32_16x16x32_bf16(af[mt], bf, acc[mt * 3 + nt], 0, 0, 0);
      }
    }
  }

  // ---- epilogue: bias + store (q pre-scaled by QSCALE for exp2 softmax) ----
#pragma unroll
  for (int nt = 0; nt < 3; nt++) {
    int idx = wv * 48 + nt * 16;
    int mat = idx >> 6;
    int h = (idx & 63) + ln;
    float bcol = ((mat == 0) ? bq : (mat == 1) ? bk : bv)[h];
#pragma unroll
    for (int mt = 0; mt < 2; mt++) {
      f32x4 a = acc[mt * 3 + nt];
      int grow0 = m0 + mt * 16 + quad * 4;
      if (mat == 0) {
#pragma unroll
        for (int r = 0; r < 4; r++)
          qb[(size_t)(grow0 + r) * 64 + h] = (__bf16)((a[r] + bcol) * QSCALE);
      } else if (mat == 1) {
#pragma unroll
        for (int r = 0; r < 4; r++)
          kb[(size_t)(grow0 + r) * 64 + h] = (__bf16)(a[r] + bcol);
      } else {
        int bb = grow0 >> 11, t0 = grow0 & 2047;
        bf16x4 pv;
#pragma unroll
        for (int r = 0; r < 4; r++)
          pv[r] = (__bf16)(a[r] + bcol);
        *(bf16x4*)(vt + (size_t)(bb * 64 + h) * T_ + t0) = pv;
      }
    }
  }
}

// ---------------------------------------------------------------------------
// Kernel 3: causal flash attention, DUAL q-tile per block (UNCHANGED from
// v7/v8/v9 for clean attribution of the proj delta).
// ---------------------------------------------------------------------------
__global__ __launch_bounds__(256)
void attn_kernel(const __bf16* __restrict__ qb,
                 const __bf16* __restrict__ kb,
                 const __bf16* __restrict__ vt,
                 float* __restrict__ out) {
  __shared__ __align__(16) __bf16 pA[2][4][16][72];  // [lo/hi][wave][row][col]
  __shared__ float ml_m[4][16];
  __shared__ float ml_l[4][16];
  __shared__ float olds[4][16][64];

  const int tid   = threadIdx.x;
  const int wv    = tid >> 6;
  const int lane  = tid & 63;
  const int ln    = lane & 15;
  const int quad  = lane >> 4;
  const int b     = blockIdx.y;

  const int p     = ((blockIdx.y >> 2) & 1) ? blockIdx.x : 63 - blockIdx.x;
  const int jqL   = p, jqH = 127 - p;
  const int qbL   = jqL * 16, qbH = jqH * 16;
  const int ntL   = (jqL >> 2) + 1;
  const int ntH   = (jqH >> 2) + 1;

  const __bf16* Q = qb + (size_t)b * T_ * 64;
  const __bf16* K = kb + (size_t)b * T_ * 64;
  const __bf16* V = vt + (size_t)b * 64 * T_;

  bf16x8 qaL0 = *(const bf16x8*)(Q + (qbL + ln) * 64 + quad * 8);
  bf16x8 qaL1 = *(const bf16x8*)(Q + (qbL + ln) * 64 + 32 + quad * 8);
  bf16x8 qaH0 = *(const bf16x8*)(Q + (qbH + ln) * 64 + quad * 8);
  bf16x8 qaH1 = *(const bf16x8*)(Q + (qbH + ln) * 64 + 32 + quad * 8);

  f32x4 accL[4] = {}, accH[4] = {};
  float mL = -INFINITY, lL = 0.f, mH = -INFINITY, lH = 0.f;

  bf16x8 kfa[4], kfb[4], vfa[4], vfb[4];
#pragma unroll
  for (int h = 0; h < 4; h++) {
    const __bf16* kr = K + (size_t)(wv * 64 + h * 16 + ln) * 64 + quad * 8;
    kfa[h] = *(const bf16x8*)kr;
    kfb[h] = *(const bf16x8*)(kr + 32);
  }

  int jt = wv;

  // ---- phase 1: both q-tiles share K/V fragments ----
  for (; jt < ntL; jt += 4) {
    const int kv0 = jt * 64;

    f32x4 sH[4] = {}, sL[4] = {};
#pragma unroll
    for (int h = 0; h < 4; h++) {
      sH[h] = __builtin_amdgcn_mfma_f32_16x16x32_bf16(kfa[h], qaH0, sH[h], 0, 0, 0);
      sH[h] = __builtin_amdgcn_mfma_f32_16x16x32_bf16(kfb[h], qaH1, sH[h], 0, 0, 0);
      sL[h] = __builtin_amdgcn_mfma_f32_16x16x32_bf16(kfa[h], qaL0, sL[h], 0, 0, 0);
      sL[h] = __builtin_amdgcn_mfma_f32_16x16x32_bf16(kfb[h], qaL1, sL[h], 0, 0, 0);
    }

    if (jt + 4 < ntH) {
#pragma unroll
      for (int h = 0; h < 4; h++) {
        const __bf16* kr = K + (size_t)(kv0 + 256 + h * 16 + ln) * 64 + quad * 8;
        kfa[h] = *(const bf16x8*)kr;
        kfb[h] = *(const bf16x8*)(kr + 32);
      }
    }
#pragma unroll
    for (int nt = 0; nt < 4; nt++) {
      const __bf16* vr = V + (size_t)(nt * 16 + ln) * T_ + kv0 + quad * 8;
      vfa[nt] = *(const bf16x8*)vr;
      vfb[nt] = *(const bf16x8*)(vr + 32);
    }

    if (jt == ntL - 1) {
      const int lim = qbL + ln - kv0 - quad * 4;
#pragma unroll
      for (int h = 0; h < 4; h++)
#pragma unroll
        for (int r = 0; r < 4; r++)
          if (h * 16 + r > lim) sL[h][r] = -INFINITY;
    }

    float mxH = sH[0][0], mxL = sL[0][0];
#pragma unroll
    for (int h = 0; h < 4; h++)
#pragma unroll
      for (int r = 0; r < 4; r++) {
        mxH = fmaxf(mxH, sH[h][r]);
        mxL = fmaxf(mxL, sL[h][r]);
      }
    mxH = fmaxf(mxH, __shfl_xor(mxH, 16));
    mxL = fmaxf(mxL, __shfl_xor(mxL, 16));
    mxH = fmaxf(mxH, __shfl_xor(mxH, 32));
    mxL = fmaxf(mxL, __shfl_xor(mxL, 32));

    float mnH = fmaxf(mH, mxH), mnL = fmaxf(mL, mxL);
    float alH = __builtin_amdgcn_exp2f(mH - mnH);
    float alL = __builtin_amdgcn_exp2f(mL - mnL);
    mH = mnH; mL = mnL;

    float pH[4][4], pL[4][4], smH = 0.f, smL = 0.f;
#pragma unroll
    for (int h = 0; h < 4; h++)
#pragma unroll
      for (int r = 0; r < 4; r++) {
        pH[h][r] = __builtin_amdgcn_exp2f(sH[h][r] - mnH);
        pL[h][r] = __builtin_amdgcn_exp2f(sL[h][r] - mnL);
        smH += pH[h][r];
        smL += pL[h][r];
      }
    smH += __shfl_xor(smH, 16);  smL += __shfl_xor(smL, 16);
    smH += __shfl_xor(smH, 32);  smL += __shfl_xor(smL, 32);
    lH = lH * alH + smH;
    lL = lL * alL + smL;

    float arH[4], arL[4];
#pragma unroll
    for (int r = 0; r < 4; r++) {
      arH[r] = __shfl(alH, quad * 4 + r);
      arL[r] = __shfl(alL, quad * 4 + r);
    }
#pragma unroll
    for (int nt = 0; nt < 4; nt++)
#pragma unroll
      for (int r = 0; r < 4; r++) {
        accH[nt][r] *= arH[r];
        accL[nt][r] *= arL[r];
      }

#pragma unroll
    for (int h = 0; h < 4; h++) {
      bf16x4 ph, pl;
#pragma unroll
      for (int r = 0; r < 4; r++) { ph[r] = (__bf16)pH[h][r]; pl[r] = (__bf16)pL[h][r]; }
      *(bf16x4*)(&pA[1][wv][ln][h * 16 + quad * 4]) = ph;
      *(bf16x4*)(&pA[0][wv][ln][h * 16 + quad * 4]) = pl;
    }
    bf16x8 paH0 = *(const bf16x8*)(&pA[1][wv][ln][quad * 8]);
    bf16x8 paH1 = *(const bf16x8*)(&pA[1][wv][ln][32 + quad * 8]);
    bf16x8 paL0 = *(const bf16x8*)(&pA[0][wv][ln][quad * 8]);
    bf16x8 paL1 = *(const bf16x8*)(&pA[0][wv][ln][32 + quad * 8]);
#pragma unroll
    for (int nt = 0; nt < 4; nt++) {
      accH[nt] = __builtin_amdgcn_mfma_f32_16x16x32_bf16(paH0, vfa[nt], accH[nt], 0, 0, 0);
      accH[nt] = __builtin_amdgcn_mfma_f32_16x16x32_bf16(paH1, vfb[nt], accH[nt], 0, 0, 0);
      accL[nt] = __builtin_amdgcn_mfma_f32_16x16x32_bf16(paL0, vfa[nt], accL[nt], 0, 0, 0);
      accL[nt] = __builtin_amdgcn_mfma_f32_16x16x32_bf16(paL1, vfb[nt], accL[nt], 0, 0, 0);
    }
  }

  // ---- phase 2: high tile only ----
  for (; jt < ntH; jt += 4) {
    const int kv0 = jt * 64;

    f32x4 sH[4] = {};
#pragma unroll
    for (int h = 0; h < 4; h++) {
      sH[h] = __builtin_amdgcn_mfma_f32_16x16x32_bf16(kfa[h], qaH0, sH[h], 0, 0, 0);
      sH[h] = __builtin_amdgcn_mfma_f32_16x16x32_bf16(kfb[h], qaH1, sH[h], 0, 0, 0);
    }

    if (jt + 4 < ntH) {
#pragma unroll
      for (int h = 0; h < 4; h++) {
        const __bf16* kr = K + (size_t)(kv0 + 256 + h * 16 + ln) * 64 + quad * 8;
        kfa[h] = *(const bf16x8*)kr;
        kfb[h] = *(const bf16x8*)(kr + 32);
      }
    }
#pragma unroll
    for (int nt = 0; nt < 4; nt++) {
      const __bf16* vr = V + (size_t)(nt * 16 + ln) * T_ + kv0 + quad * 8;
      vfa[nt] = *(const bf16x8*)vr;
      vfb[nt] = *(const bf16x8*)(vr + 32);
    }

    if (jt == ntH - 1) {
      const int lim = qbH + ln - kv0 - quad * 4;
#pragma unroll
      for (int h = 0; h < 4; h++)
#pragma unroll
        for (int r = 0; r < 4; r++)
          if (h * 16 + r > lim) sH[h][r] = -INFINITY;
    }

    float mxH = sH[0][0];
#pragma unroll
    for (int h = 0; h < 4; h++)
#pragma unroll
      for (int r = 0; r < 4; r++) mxH = fmaxf(mxH, sH[h][r]);
    mxH = fmaxf(mxH, __shfl_xor(mxH, 16));
    mxH = fmaxf(mxH, __shfl_xor(mxH, 32));

    float mnH = fmaxf(mH, mxH);
    float alH = __builtin_amdgcn_exp2f(mH - mnH);
    mH = mnH;

    float pH[4][4], smH = 0.f;
#pragma unroll
    for (int h = 0; h < 4; h++)
#pragma unroll
      for (int r = 0; r < 4; r++) {
        pH[h][r] = __builtin_amdgcn_exp2f(sH[h][r] - mnH);
        smH += pH[h][r];
      }
    smH += __shfl_xor(smH, 16);
    smH += __shfl_xor(smH, 32);
    lH = lH * alH + smH;

    float arH[4];
#pragma unroll
    for (int r = 0; r < 4; r++) arH[r] = __shfl(alH, quad * 4 + r);
#pragma unroll
    for (int nt = 0; nt < 4; nt++)
#pragma unroll
      for (int r = 0; r < 4; r++) accH[nt][r] *= arH[r];

#pragma unroll
    for (int h = 0; h < 4; h++) {
      bf16x4 ph;
#pragma unroll
      for (int r = 0; r < 4; r++) ph[r] = (__bf16)pH[h][r];
      *(bf16x4*)(&pA[1][wv][ln][h * 16 + quad * 4]) = ph;
    }
    bf16x8 paH0 = *(const bf16x8*)(&pA[1][wv][ln][quad * 8]);
    bf16x8 paH1 = *(const bf16x8*)(&pA[1][wv][ln][32 + quad * 8]);
#pragma unroll
    for (int nt = 0; nt < 4; nt++) {
      accH[nt] = __builtin_amdgcn_mfma_f32_16x16x32_bf16(paH0, vfa[nt], accH[nt], 0, 0, 0);
      accH[nt] = __builtin_amdgcn_mfma_f32_16x16x32_bf16(paH1, vfb[nt], accH[nt], 0, 0, 0);
    }
  }

  // ---- merge + store: low tile, then high tile (sequential LDS reuse) ----
#pragma unroll
  for (int side = 0; side < 2; side++) {
    const float m_i = side == 0 ? mL : mH;
    const float l_i = side == 0 ? lL : lH;
    const f32x4* acc = side == 0 ? accL : accH;
    const int qbase  = side == 0 ? qbL : qbH;

    __syncthreads();
    if (quad == 0) {
      ml_m[wv][ln] = m_i;
      ml_l[wv][ln] = l_i;
    }
    __syncthreads();

#pragma unroll
    for (int r = 0; r < 4; r++) {
      int row = quad * 4 + r;
      float mstar = fmaxf(fmaxf(ml_m[0][row], ml_m[1][row]),
                          fmaxf(ml_m[2][row], ml_m[3][row]));
      float factor = __builtin_amdgcn_exp2f(ml_m[wv][row] - mstar);
#pragma unroll
      for (int nt = 0; nt < 4; nt++)
        olds[wv][row][nt * 16 + ln] = acc[nt][r] * factor;
    }
    __syncthreads();

    {
      int row = tid >> 4;
      int h0 = (tid & 15) * 4;
      float mstar = fmaxf(fmaxf(ml_m[0][row], ml_m[1][row]),
                          fmaxf(ml_m[2][row], ml_m[3][row]));
      float ltot = 0.f;
#pragma unroll
      for (int w = 0; w < 4; w++)
        ltot += ml_l[w][row] * __builtin_amdgcn_exp2f(ml_m[w][row] - mstar);
      float inv = 1.0f / ltot;
      float4 o = {0.f, 0.f, 0.f, 0.f};
#pragma unroll
      for (int w = 0; w < 4; w++) {
        float4 t = *(const float4*)(&olds[w][row][h0]);
        o.x += t.x; o.y += t.y; o.z += t.z; o.w += t.w;
      }
      o.x *= inv; o.y *= inv; o.z *= inv; o.w *= inv;
      *(float4*)(out + ((size_t)(b * T_ + qbase + row)) * 64 + h0) = o;
    }
  }
}

// ---------------------------------------------------------------------------
extern "C" void kernel_launch(void* const* d_in, const int* in_sizes, int n_in,
                              void* d_out, int out_size, void* d_ws, size_t ws_size,
                              hipStream_t stream) {
  const float* x  = (const float*)d_in[0];
  const float* Wk = (const float*)d_in[1];
  const float* bk = (const float*)d_in[2];
  const float* Wq = (const float*)d_in[3];
  const float* bq = (const float*)d_in[4];
  const float* Wv = (const float*)d_in[5];
  const float* bv = (const float*)d_in[6];
  float* out = (float*)d_out;

  char* ws = (char*)d_ws;
  __bf16* qb = (__bf16*)(ws);                                  // 2 MB (pre-scaled)
  __bf16* kb = (__bf16*)(ws + (size_t)2 * 1024 * 1024);        // 2 MB
  __bf16* vt = (__bf16*)(ws + (size_t)4 * 1024 * 1024);        // 2 MB (transposed)
  __bf16* Wt = (__bf16*)(ws + (size_t)6 * 1024 * 1024);        // 384 KB

  castw_kernel<<<dim3(16, 3), 256, 0, stream>>>(Wq, Wk, Wv, Wt);
  proj_kernel<<<512, 256, 0, stream>>>(x, Wt, bq, bk, bv, qb, kb, vt);
  attn_kernel<<<dim3(64, 8), 256, 0, stream>>>(qb, kb, vt, out);
}